// Round 5
// baseline (304.940 us; speedup 1.0000x reference)
//
#include <hip/hip_runtime.h>
#include <math.h>

#define NN 4096
#define EE 8192
#define HH 128
#define GG 8
#define ULD 4352          // big GEMM cols: 4096 (W2) + 128 (b2) + 128 (root)

typedef __attribute__((ext_vector_type(8))) _Float16 half8;
typedef __attribute__((ext_vector_type(4))) float floatx4;

__device__ __forceinline__ void ldst16(const _Float16* g, void* l) {
    __builtin_amdgcn_global_load_lds(
        (const __attribute__((address_space(1))) unsigned int*)g,
        (__attribute__((address_space(3))) unsigned int*)l, 16, 0, 0);
}

// ---------------------------------------------------------------------------
// fp16 MFMA GEMM: C[M,ULD] = A[M,128] @ BT[N,128]^T, C stored fp16.
// 128x128 tile/block, 4 waves (2x2 of 64x64), BK=32, K=128 (4 iters).
// Epilogue restages C through LDS so global stores are dwordx4 (16B),
// not 2B scalars (8x fewer store instructions — R4's bottleneck).
// ---------------------------------------------------------------------------
__global__ __launch_bounds__(256) void mgemm16_k(
    const _Float16* __restrict__ A, const _Float16* __restrict__ B,
    _Float16* __restrict__ C)
{
    __shared__ __align__(16) _Float16 As[128 * 32];  // [row][k]
    __shared__ __align__(16) _Float16 Bs[128 * 32];  // [col][k]
    __shared__ __align__(16) _Float16 Cs[128 * 136]; // [row][col], pad 8
    const int tid = threadIdx.x;
    const int lane = tid & 63, wave = tid >> 6;
    const int m0 = blockIdx.y * 128, n0 = blockIdx.x * 128;
    const int wr = (wave >> 1) * 64, wc = (wave & 1) * 64;
    const int fm = lane & 15, fq = lane >> 4;

    const int srow = tid >> 2, soff = (tid & 3) << 3;
    const _Float16* gA0 = A + (size_t)(m0 + srow) * 128 + soff;
    const _Float16* gA1 = gA0 + (size_t)64 * 128;
    const _Float16* gB0 = B + (size_t)(n0 + srow) * 128 + soff;
    const _Float16* gB1 = gB0 + (size_t)64 * 128;
    char* lA0 = (char*)As + tid * 16;  char* lA1 = (char*)As + (tid + 256) * 16;
    char* lB0 = (char*)Bs + tid * 16;  char* lB1 = (char*)Bs + (tid + 256) * 16;

    floatx4 acc[4][4] = {};
    for (int k0 = 0; k0 < 128; k0 += 32) {
        __syncthreads();
        ldst16(gA0 + k0, lA0); ldst16(gA1 + k0, lA1);
        ldst16(gB0 + k0, lB0); ldst16(gB1 + k0, lB1);
        __syncthreads();
        half8 af[4], bf[4];
#pragma unroll
        for (int i = 0; i < 4; ++i)
            af[i] = *(const half8*)&As[(wr + i * 16 + fm) * 32 + fq * 8];
#pragma unroll
        for (int j = 0; j < 4; ++j)
            bf[j] = *(const half8*)&Bs[(wc + j * 16 + fm) * 32 + fq * 8];
#pragma unroll
        for (int i = 0; i < 4; ++i)
#pragma unroll
            for (int j = 0; j < 4; ++j)
                acc[i][j] = __builtin_amdgcn_mfma_f32_16x16x32_f16(
                    af[i], bf[j], acc[i][j], 0, 0, 0);
    }
    // C/D layout: col = lane&15, row = (lane>>4)*4 + reg  [m89; dtype-indep]
#pragma unroll
    for (int i = 0; i < 4; ++i)
#pragma unroll
        for (int j = 0; j < 4; ++j)
#pragma unroll
            for (int r = 0; r < 4; ++r)
                Cs[(wr + i * 16 + fq * 4 + r) * 136 + wc + j * 16 + fm] =
                    (_Float16)acc[i][j][r];
    __syncthreads();
    const int row = tid >> 1, hf = tid & 1;
    const _Float16* src = &Cs[row * 136 + hf * 64];
    _Float16* dst = &C[(size_t)(m0 + row) * ULD + n0 + hf * 64];
#pragma unroll
    for (int u = 0; u < 8; ++u)
        *(half8*)&dst[u * 8] = *(const half8*)&src[u * 8];
}

// ---------------------------------------------------------------------------
// GRU GEMM, both gates in one dispatch via blockIdx.z, with mcomb fused into
// the z=0 A-staging (vectorized half8/float4 loads).
// ---------------------------------------------------------------------------
__global__ __launch_bounds__(256) void gru_k(
    const _Float16* __restrict__ bigC, const float* __restrict__ agg,
    const float* __restrict__ cb, const _Float16* __restrict__ Ax,
    const _Float16* __restrict__ Bih, const _Float16* __restrict__ Bhh,
    const float* __restrict__ bih, const float* __restrict__ bhh,
    float* __restrict__ g1, float* __restrict__ g2)
{
    const int z = blockIdx.z;
    const _Float16* B = z ? Bhh : Bih;
    const float* bias = z ? bhh : bih;
    float* C = z ? g2 : g1;

    __shared__ __align__(16) _Float16 As[128 * 40];
    __shared__ __align__(16) _Float16 Bs[128 * 40];
    const int tid = threadIdx.x;
    const int lane = tid & 63, wave = tid >> 6;
    const int m0 = blockIdx.y * 128, n0 = blockIdx.x * 128;
    const int wr = (wave >> 1) * 64, wc = (wave & 1) * 64;
    const int fm = lane & 15, fq = lane >> 4;

    floatx4 acc[4][4] = {};
    for (int k0 = 0; k0 < 128; k0 += 32) {
        __syncthreads();
#pragma unroll
        for (int c = tid; c < 512; c += 256) {
            const int row = c >> 2, seg = (c & 3) << 3;
            if (z == 0) {
                const int mr = m0 + row;
                const half8 bv = *(const half8*)&bigC[(size_t)mr * ULD + 4224 + k0 + seg];
                const float4 a0 = *(const float4*)&agg[(size_t)mr * 128 + k0 + seg];
                const float4 a1 = *(const float4*)&agg[(size_t)mr * 128 + k0 + seg + 4];
                const float4 c0 = *(const float4*)&cb[k0 + seg];
                const float4 c1 = *(const float4*)&cb[k0 + seg + 4];
                _Float16 v8[8];
                v8[0] = (_Float16)fmaxf((float)bv[0] + a0.x + c0.x, 0.f);
                v8[1] = (_Float16)fmaxf((float)bv[1] + a0.y + c0.y, 0.f);
                v8[2] = (_Float16)fmaxf((float)bv[2] + a0.z + c0.z, 0.f);
                v8[3] = (_Float16)fmaxf((float)bv[3] + a0.w + c0.w, 0.f);
                v8[4] = (_Float16)fmaxf((float)bv[4] + a1.x + c1.x, 0.f);
                v8[5] = (_Float16)fmaxf((float)bv[5] + a1.y + c1.y, 0.f);
                v8[6] = (_Float16)fmaxf((float)bv[6] + a1.z + c1.z, 0.f);
                v8[7] = (_Float16)fmaxf((float)bv[7] + a1.w + c1.w, 0.f);
                *(half8*)&As[row * 40 + seg] = *(half8*)v8;
            } else {
                *(half8*)&As[row * 40 + seg] =
                    *(const half8*)&Ax[(size_t)(m0 + row) * 128 + k0 + seg];
            }
            *(half8*)&Bs[row * 40 + seg] =
                *(const half8*)&B[(size_t)(n0 + row) * 128 + k0 + seg];
        }
        __syncthreads();
        half8 af[4], bf[4];
#pragma unroll
        for (int i = 0; i < 4; ++i)
            af[i] = *(const half8*)&As[(wr + i * 16 + fm) * 40 + fq * 8];
#pragma unroll
        for (int j = 0; j < 4; ++j)
            bf[j] = *(const half8*)&Bs[(wc + j * 16 + fm) * 40 + fq * 8];
#pragma unroll
        for (int i = 0; i < 4; ++i)
#pragma unroll
            for (int j = 0; j < 4; ++j)
                acc[i][j] = __builtin_amdgcn_mfma_f32_16x16x32_f16(
                    af[i], bf[j], acc[i][j], 0, 0, 0);
    }
    const int er = fq * 4, ec = fm;
#pragma unroll
    for (int i = 0; i < 4; ++i) {
        const int gr = m0 + wr + i * 16 + er;
#pragma unroll
        for (int j = 0; j < 4; ++j) {
            const int gc = n0 + wc + j * 16 + ec;
            const float bv = bias[gc];
#pragma unroll
            for (int r = 0; r < 4; ++r)
                C[(size_t)(gr + r) * 384 + gc] = acc[i][j][r] + bv;
        }
    }
}

// ---------------------------------------------------------------------------
// lin0: xh = relu(x[4096,64] @ w[64,128] + b) fp32; also writes Ax fp16.
// ---------------------------------------------------------------------------
__global__ __launch_bounds__(256) void lin0_k(
    const float* __restrict__ Ag, const float* __restrict__ Bg,
    const float* __restrict__ bias, float* __restrict__ xh,
    _Float16* __restrict__ Ax)
{
    __shared__ float As[16][64];
    __shared__ float Bs[16][64];
    const int tid = threadIdx.x;
    const int tx = tid & 15, ty = tid >> 4;
    const int j0 = blockIdx.x * 64;
    const int m0 = blockIdx.y * 64;
    const int arow = tid >> 2, acol = (tid & 3) << 2;
    const int bk = tid >> 4, bj = (tid & 15) << 2;

    float c[4][4] = {};
    for (int k0 = 0; k0 < 64; k0 += 16) {
        __syncthreads();
        float4 av = *(const float4*)&Ag[(size_t)(m0 + arow) * 64 + k0 + acol];
        As[acol + 0][arow] = av.x;
        As[acol + 1][arow] = av.y;
        As[acol + 2][arow] = av.z;
        As[acol + 3][arow] = av.w;
        *(float4*)&Bs[bk][bj] = *(const float4*)&Bg[(size_t)(k0 + bk) * 128 + j0 + bj];
        __syncthreads();
#pragma unroll
        for (int kk = 0; kk < 16; ++kk) {
            const float4 a = *(const float4*)&As[kk][ty << 2];
            const float4 b = *(const float4*)&Bs[kk][tx << 2];
            c[0][0] += a.x * b.x; c[0][1] += a.x * b.y; c[0][2] += a.x * b.z; c[0][3] += a.x * b.w;
            c[1][0] += a.y * b.x; c[1][1] += a.y * b.y; c[1][2] += a.y * b.z; c[1][3] += a.y * b.w;
            c[2][0] += a.z * b.x; c[2][1] += a.z * b.y; c[2][2] += a.z * b.z; c[2][3] += a.z * b.w;
            c[3][0] += a.w * b.x; c[3][1] += a.w * b.y; c[3][2] += a.w * b.z; c[3][3] += a.w * b.w;
        }
    }
    const float4 bv = *(const float4*)&bias[j0 + (tx << 2)];
    const int col0 = j0 + (tx << 2);
#pragma unroll
    for (int i = 0; i < 4; ++i) {
        const int row = m0 + (ty << 2) + i;
        float4 o;
        o.x = fmaxf(c[i][0] + bv.x, 0.f); o.y = fmaxf(c[i][1] + bv.y, 0.f);
        o.z = fmaxf(c[i][2] + bv.z, 0.f); o.w = fmaxf(c[i][3] + bv.w, 0.f);
        *(float4*)&xh[(size_t)row * 128 + col0] = o;
        _Float16* base = Ax + (size_t)row * 128 + col0;
        base[0] = (_Float16)o.x; base[1] = (_Float16)o.y;
        base[2] = (_Float16)o.z; base[3] = (_Float16)o.w;
    }
}

// ---------------------------------------------------------------------------
// setup: GRU weight fp32->fp16 cast + degree/out-degree/graph-count hists
// ---------------------------------------------------------------------------
__global__ __launch_bounds__(256) void setup_k(
    const float* __restrict__ wih, const float* __restrict__ whh,
    _Float16* __restrict__ Bih, _Float16* __restrict__ Bhh,
    const int* __restrict__ ei, const int* __restrict__ batch,
    float* __restrict__ deg, int* __restrict__ odeg, float* __restrict__ cnt)
{
    __shared__ float loc8[GG];
    const int b = blockIdx.x, t = threadIdx.x;
    if (b < 192) {
        const int idx = b * 256 + t;           // 384*128
        Bih[idx] = (_Float16)wih[idx];
        Bhh[idx] = (_Float16)whh[idx];
    } else if (b < 224) {
        const int e = (b - 192) * 256 + t;     // 8192
        atomicAdd(&deg[ei[EE + e]], 1.0f);
        atomicAdd(&odeg[ei[e]], 1);
    } else {
        const int n = (b - 224) * 256 + t;     // 4096
        if (t < GG) loc8[t] = 0.f;
        __syncthreads();
        atomicAdd(&loc8[batch[n]], 1.0f);
        __syncthreads();
        if (t < GG) atomicAdd(&cnt[t], loc8[t]);
    }
}

// exclusive prefix sum of odeg[4096] -> ocur (single block)
__global__ __launch_bounds__(256) void scan_k(const int* __restrict__ odeg,
                                              int* __restrict__ ocur) {
    __shared__ int ps[256];
    const int t = threadIdx.x;
    const int base = t * 16;
    int l[16]; int s = 0;
#pragma unroll
    for (int i = 0; i < 16; ++i) { l[i] = s; s += odeg[base + i]; }
    ps[t] = s;
    __syncthreads();
    for (int d = 1; d < 256; d <<= 1) {
        int v = (t >= d) ? ps[t - d] : 0;
        __syncthreads();
        ps[t] += v;
        __syncthreads();
    }
    const int excl = (t == 0) ? 0 : ps[t - 1];
#pragma unroll
    for (int i = 0; i < 16; ++i) ocur[base + i] = excl + l[i];
}

// counting-sort scatter by source + per-edge coefficient tables (sorted order)
__global__ void scatter_k(const int* __restrict__ ei, const float* __restrict__ eattr,
                          const float* __restrict__ w1, const float* __restrict__ b1,
                          const float* __restrict__ deg, int* __restrict__ ocur,
                          int2* __restrict__ rc, float* __restrict__ ehP) {
    const int e = blockIdx.x * 256 + threadIdx.x;
    const int r = ei[e], c = ei[EE + e];
    const int pos = atomicAdd(&ocur[r], 1);
    rc[pos] = make_int2(r, c);
    const float d = deg[c];
    const float inv = d > 0.f ? 1.0f / d : 0.0f;
    const float ea = eattr[e];
    for (int t = 0; t < 3; ++t) {
        float* dst = ehP + ((size_t)t * EE + pos) * 33;
        for (int k = 0; k < 32; ++k) {
            float v = ea * w1[t * 32 + k] + b1[t * 32 + k];
            dst[k] = (v > 0.f ? v : 0.f) * inv;
        }
        dst[32] = inv;
    }
}

// ---------------------------------------------------------------------------
// Edge gather + scatter. Each block: 2 edges. The 8448B contiguous U-slab of
// each edge is cooperatively loaded to LDS with 16B vector loads, then each
// thread computes one output column from LDS (2-way bank alias = free).
// ---------------------------------------------------------------------------
__global__ __launch_bounds__(256) void edge_msg_k(
    const int2* __restrict__ rc, const float* __restrict__ ehP,
    const _Float16* __restrict__ U, float* __restrict__ agg)
{
    __shared__ __align__(16) _Float16 slab[2][4224];
    __shared__ float ehs[2][33];
    const int tid = threadIdx.x;
    const int b = blockIdx.x;                      // 4096 pairs
    const int p0 = ((b & 7) * 512 + (b >> 3)) * 2; // XCD-contiguous sorted ranges
    const int2 e0 = rc[p0];
    const int2 e1 = rc[p0 + 1];
    if (tid < 66) {
        const int h = tid >= 33;
        ehs[h][tid - h * 33] = ehP[(size_t)(p0 + h) * 33 + (tid - h * 33)];
    }
    const _Float16* base0 = U + (size_t)e0.x * ULD;
    const _Float16* base1 = U + (size_t)e1.x * ULD;
#pragma unroll
    for (int c = tid; c < 1056; c += 256) {
        const int ed = c >= 528;
        const int chunk = c - ed * 528;
        *(half8*)&slab[ed][chunk * 8] =
            *(const half8*)&(ed ? base1 : base0)[chunk * 8];
    }
    __syncthreads();
    const int half = tid >> 7;
    const int o = tid & 127;
    const float* eh = ehs[half];
    const _Float16* sl = slab[half];
    float acc = eh[32] * (float)sl[4096 + o];
#pragma unroll
    for (int k = 0; k < 32; ++k) acc += eh[k] * (float)sl[k * 128 + o];
    const int col = half ? e1.y : e0.y;
    atomicAdd(&agg[(size_t)col * 128 + o], acc);
}

// GRU gate combine; updates xh fp32 + Ax fp16; fused pooling on last step
__global__ void gate_k(const float* __restrict__ G1, const float* __restrict__ G2,
                       float* __restrict__ xh, _Float16* __restrict__ Ax,
                       const int* __restrict__ batch, float* __restrict__ pooled) {
    const int idx = blockIdx.x * 256 + threadIdx.x;
    const int n = idx >> 7, o = idx & 127;
    const size_t b = (size_t)n * 384;
    float ir = G1[b + o], iz = G1[b + 128 + o], in_ = G1[b + 256 + o];
    float hr = G2[b + o], hz = G2[b + 128 + o], hn = G2[b + 256 + o];
    float r = 1.f / (1.f + expf(-(ir + hr)));
    float z = 1.f / (1.f + expf(-(iz + hz)));
    float nv = tanhf(in_ + r * hn);
    float hv = (1.f - z) * nv + z * xh[idx];
    xh[idx] = hv;
    Ax[idx] = (_Float16)hv;
    if (pooled) atomicAdd(&pooled[batch[n] * 128 + o], hv);
}

// Big B'T[t][j(4352)][128] fp16: j<4096 -> W2; <4224 -> b2; else root_w
__global__ void convb_big_k(const float* __restrict__ w2, const float* __restrict__ b2,
                            const float* __restrict__ rw, _Float16* __restrict__ BT) {
    const int t = blockIdx.y;
    const int idx = blockIdx.x * 256 + threadIdx.x;   // 4352*128
    const int j = idx >> 7, h = idx & 127;
    float v;
    if (j < 4096)      v = w2[(size_t)t * 524288 + (size_t)(j >> 7) * 16384 + h * 128 + (j & 127)];
    else if (j < 4224) v = b2[t * 16384 + h * 128 + (j - 4096)];
    else               v = rw[t * 16384 + h * 128 + (j - 4224)];
    BT[(size_t)t * 557056 + (size_t)j * 128 + h] = (_Float16)v;
}

__global__ __launch_bounds__(128) void final_k(
    const float* __restrict__ pooled, const float* __restrict__ cnt,
    const float* __restrict__ l1w, const float* __restrict__ l1b,
    const float* __restrict__ l2w, const float* __restrict__ l2b,
    float* __restrict__ out)
{
    __shared__ float gv[128];
    __shared__ float sy[64];
    const int t = threadIdx.x;
    for (int g = 0; g < GG; ++g) {
        float c = cnt[g]; c = c > 1.f ? c : 1.f;
        gv[t] = pooled[g * 128 + t] / c;
        __syncthreads();
        if (t < 64) {
            float y = l1b[t];
            for (int h = 0; h < 128; ++h) y += gv[h] * l1w[h * 64 + t];
            y = y > 0.f ? y : 0.f;
            sy[t] = y * l2w[t];
        }
        __syncthreads();
        if (t == 0) {
            float s = l2b[0];
            for (int j = 0; j < 64; ++j) s += sy[j];
            out[g] = s;
        }
        __syncthreads();
    }
}

extern "C" void kernel_launch(void* const* d_in, const int* in_sizes, int n_in,
                              void* d_out, int out_size, void* d_ws, size_t ws_size,
                              hipStream_t stream) {
    const float* x      = (const float*)d_in[0];
    const int*   ei     = (const int*)d_in[1];
    const float* eattr  = (const float*)d_in[2];
    const int*   batch  = (const int*)d_in[3];
    const float* lin0_w = (const float*)d_in[4];
    const float* lin0_b = (const float*)d_in[5];
    const float* nn_w1  = (const float*)d_in[6];
    const float* nn_b1  = (const float*)d_in[7];
    const float* nn_w2  = (const float*)d_in[8];
    const float* nn_b2  = (const float*)d_in[9];
    const float* root_w = (const float*)d_in[10];
    const float* conv_b = (const float*)d_in[11];
    const float* gwih   = (const float*)d_in[12];
    const float* gwhh   = (const float*)d_in[13];
    const float* gbih   = (const float*)d_in[14];
    const float* gbhh   = (const float*)d_in[15];
    const float* l1w    = (const float*)d_in[16];
    const float* l1b    = (const float*)d_in[17];
    const float* l2w    = (const float*)d_in[18];
    const float* l2b    = (const float*)d_in[19];
    float* out = (float*)d_out;
    float* ws  = (float*)d_ws;

    // ---- workspace layout (float offsets; zero region first, contiguous) ----
    float*    agg0   = ws;                          // 3 x [4096,128]
    float*    pooled = ws + 1572864;                // [8,128]
    float*    cnt    = ws + 1573888;                // [8]
    float*    deg    = ws + 1573896;                // [4096]
    int*      odeg   = (int*)(ws + 1577992);        // [4096]
    // zero region ends at 1582088 floats = 6328352 bytes
    int*      ocur   = (int*)(ws + 1582088);        // [4096]
    int2*     rc     = (int2*)(ws + 1586184);       // [8192]
    float*    ehP    = ws + 1602568;                // [3,8192,33]
    float*    xh     = ws + 2413576;                // [4096,128]
    float*    g1     = ws + 2937864;                // [4096,384]
    float*    g2     = ws + 4510728;                // [4096,384]
    _Float16* bigC   = (_Float16*)(ws + 6083592);   // [4096,4352] fp16
    _Float16* Ax     = (_Float16*)(ws + 14996488);  // [4096,128] fp16
    _Float16* BTu    = (_Float16*)(ws + 15258632);  // 3 x [4352,128] fp16
    _Float16* Bih16  = (_Float16*)(ws + 16094216);  // [384,128] fp16
    _Float16* Bhh16  = (_Float16*)(ws + 16118792);  // [384,128] fp16

    hipMemsetAsync(agg0, 0, 6328352, stream);
    setup_k<<<240, 256, 0, stream>>>(gwih, gwhh, Bih16, Bhh16, ei, batch, deg, odeg, cnt);
    scan_k<<<1, 256, 0, stream>>>(odeg, ocur);
    scatter_k<<<EE / 256, 256, 0, stream>>>(ei, eattr, nn_w1, nn_b1, deg, ocur, rc, ehP);
    convb_big_k<<<dim3(2176, 3), 256, 0, stream>>>(nn_w2, nn_b2, root_w, BTu);
    lin0_k<<<dim3(2, 64), 256, 0, stream>>>(x, lin0_w, lin0_b, xh, Ax);

    for (int t = 0; t < 3; ++t) {
        float* agg = agg0 + (size_t)t * 524288;
        mgemm16_k<<<dim3(34, 32), 256, 0, stream>>>(Ax, BTu + (size_t)t * 557056, bigC);
        edge_msg_k<<<EE / 2, 256, 0, stream>>>(rc, ehP + (size_t)t * EE * 33, bigC, agg);
        gru_k<<<dim3(3, 32, 2), 256, 0, stream>>>(bigC, agg, conv_b + t * 128, Ax,
                                                  Bih16, Bhh16, gbih, gbhh, g1, g2);
        gate_k<<<2048, 256, 0, stream>>>(g1, g2, xh, Ax, batch,
                                         (t == 2) ? pooled : nullptr);
    }

    final_k<<<1, 128, 0, stream>>>(pooled, cnt, l1w, l1b, l2w, l2b, out);
}